// Round 8
// baseline (100.095 us; speedup 1.0000x reference)
//
#include <hip/hip_runtime.h>
#include <stdint.h>

#define S_LEN 2048
#define EMB 1024

typedef __bf16 bf16x8 __attribute__((ext_vector_type(8)));
typedef __bf16 bf16x4 __attribute__((ext_vector_type(4)));
typedef float f32x4 __attribute__((ext_vector_type(4)));

__device__ __forceinline__ unsigned short f2bf(float f) {
  unsigned int b = __float_as_uint(f);
  b += 0x7FFFu + ((b >> 16) & 1u);
  return (unsigned short)(b >> 16);
}

__device__ __forceinline__ bf16x8 cvt8(float4 a, float4 b) {
  bf16x8 r;
  r[0] = (__bf16)a.x; r[1] = (__bf16)a.y; r[2] = (__bf16)a.z; r[3] = (__bf16)a.w;
  r[4] = (__bf16)b.x; r[5] = (__bf16)b.y; r[6] = (__bf16)b.z; r[7] = (__bf16)b.w;
  return r;
}

#define GLD16(gp, lp)                                                          \
  __builtin_amdgcn_global_load_lds(                                            \
      (const __attribute__((address_space(1))) void*)(gp),                     \
      (__attribute__((address_space(3))) void*)(lp), 16, 0, 0)

// ---------------------------------------------------------------------------
// Kernel 1: per-(n,s) 16x16 head-Gram attention. One wave per position,
// 4 waves/block, barrier-free. VMEM-instruction-minimized: V goes through a
// coalesced-load -> linear bf16 LDS -> scalar ds_read path (32 global dword
// loads replaced by 4 dwordx4 + cheap DS ops). Q/K fragments direct from
// global; softmax + As round-trip identical to the round-5 verified version.
// ---------------------------------------------------------------------------
__global__ __launch_bounds__(256) void attn_kernel(
    const float* __restrict__ Q, const float* __restrict__ K,
    const float* __restrict__ V, const int* __restrict__ mask,
    __bf16* __restrict__ X) {
  __shared__ __bf16 Vb[4][1024];      // per-wave V row, linear bf16
  __shared__ __bf16 As[4][16][16];    // per-wave attention tile A[i][j]

  const int lane = threadIdx.x & 63;
  const int wv = threadIdx.x >> 6;
  const int pos = blockIdx.x * 4 + wv;  // 0..16383
  const int n = pos >> 11;
  const int s = pos & 2047;
  const int col = lane & 15;
  const int grp = lane >> 4;
  const int gc = grp & 1;
  const int fo = col * 64 + grp * 8;

  const float* qrow = Q + (size_t)pos * EMB;
  const float* krow = K + (size_t)pos * EMB;
  const float* vrow = V + (size_t)pos * EMB;

  // ---- Phase A: issue ALL VMEM loads (V coalesced first, then Q/K frags) ----
  float4 vload[4];
#pragma unroll
  for (int c = 0; c < 4; ++c)
    vload[c] = *(const float4*)(vrow + c * 256 + lane * 4);

  float4 qraw[4], kraw[4];
#pragma unroll
  for (int t = 0; t < 2; ++t) {
    qraw[t * 2 + 0] = *(const float4*)(qrow + fo + t * 32);
    qraw[t * 2 + 1] = *(const float4*)(qrow + fo + t * 32 + 4);
    kraw[t * 2 + 0] = *(const float4*)(krow + fo + t * 32);
    kraw[t * 2 + 1] = *(const float4*)(krow + fo + t * 32 + 4);
  }
  const int4 mrow = *(const int4*)(mask + col * 16 + grp * 4);
  __builtin_amdgcn_sched_barrier(0);

  // ---- Phase B: V cvt + linear LDS write (waits only V's vmcnt slots) ----
#pragma unroll
  for (int c = 0; c < 4; ++c) {
    bf16x4 w;
    w[0] = (__bf16)vload[c].x;
    w[1] = (__bf16)vload[c].y;
    w[2] = (__bf16)vload[c].z;
    w[3] = (__bf16)vload[c].w;
    *(bf16x4*)&Vb[wv][c * 256 + lane * 4] = w;
  }

  // ---- Phase C: QK^T (swapped operands) + softmax + As round-trip ----
  const bf16x8 qa0 = cvt8(qraw[0], qraw[1]);
  const bf16x8 qa1 = cvt8(qraw[2], qraw[3]);
  const bf16x8 kb0 = cvt8(kraw[0], kraw[1]);
  const bf16x8 kb1 = cvt8(kraw[2], kraw[3]);
  f32x4 en = {0.f, 0.f, 0.f, 0.f};
  en = __builtin_amdgcn_mfma_f32_16x16x32_bf16(kb0, qa0, en, 0, 0, 0);
  en = __builtin_amdgcn_mfma_f32_16x16x32_bf16(kb1, qa1, en, 0, 0, 0);
  // lane holds E[j=grp*4+r][i=col]

  float p[4];
  p[0] = (mrow.x == 0) ? -1e30f : en[0] * 0.125f;
  p[1] = (mrow.y == 0) ? -1e30f : en[1] * 0.125f;
  p[2] = (mrow.z == 0) ? -1e30f : en[2] * 0.125f;
  p[3] = (mrow.w == 0) ? -1e30f : en[3] * 0.125f;
  float mx = fmaxf(fmaxf(p[0], p[1]), fmaxf(p[2], p[3]));
  mx = fmaxf(mx, __shfl_xor(mx, 16));
  mx = fmaxf(mx, __shfl_xor(mx, 32));
  float ex[4], sm = 0.f;
#pragma unroll
  for (int r = 0; r < 4; ++r) {
    ex[r] = __expf(p[r] - mx);
    sm += ex[r];
  }
  sm += __shfl_xor(sm, 16);
  sm += __shfl_xor(sm, 32);
  const float inv = __builtin_amdgcn_rcpf(sm);
  bf16x4 aw;
#pragma unroll
  for (int r = 0; r < 4; ++r) aw[r] = (__bf16)(ex[r] * inv);
  *(bf16x4*)&As[wv][col][grp * 4] = aw;  // A[col][grp*4 + r]

  // lane needs pa[e] = A[col][grp*8+e] for grp<2; zero-pad k>=16
  const bf16x8 pt = *(const bf16x8*)&As[wv][col][gc * 8];
  bf16x8 pa;
#pragma unroll
  for (int e = 0; e < 8; ++e) pa[e] = (grp < 2) ? pt[e] : (__bf16)0.f;

  // ---- Phase D: V fragments from LDS (scalar reads) + PV + stores ----
  // lane supplies Amat[row=col][k=grp*8+e] = V[gc*8+e][d = c*16 + col]
  const size_t xrow = (size_t)n * S_LEN + (size_t)col * 128 + (s >> 4);
  __bf16* xp = X + xrow * EMB + (size_t)((s & 15) * 64 + grp * 4);
#pragma unroll
  for (int c = 0; c < 4; ++c) {
    bf16x8 vf;
#pragma unroll
    for (int e = 0; e < 8; ++e)
      vf[e] = Vb[wv][(gc * 8 + e) * 64 + c * 16 + col];
    f32x4 o = {0.f, 0.f, 0.f, 0.f};
    o = __builtin_amdgcn_mfma_f32_16x16x32_bf16(vf, pa, o, 0, 0, 0);
    // lane holds O[i=col][d = c*16 + grp*4 + r]
    bf16x4 w;
#pragma unroll
    for (int r = 0; r < 4; ++r) w[r] = (__bf16)o[r];
    *(bf16x4*)(xp + c * 16) = w;
  }
}

// ---------------------------------------------------------------------------
// Kernel 2: W_out fp32 -> bf16 bits
// ---------------------------------------------------------------------------
__global__ __launch_bounds__(256) void wconv_kernel(
    const float* __restrict__ W, unsigned short* __restrict__ Wb) {
  const int idx = blockIdx.x * 256 + threadIdx.x;
  float4 w = *(const float4*)(W + (size_t)idx * 4);
  ushort4 o;
  o.x = f2bf(w.x);
  o.y = f2bf(w.y);
  o.z = f2bf(w.z);
  o.w = f2bf(w.w);
  *(ushort4*)(Wb + (size_t)idx * 4) = o;
}

// ---------------------------------------------------------------------------
// Kernel 3: C[16384][1024] = X[16384][1024] * W[1024][1024]^T + bias
// ---------------------------------------------------------------------------
__global__ __launch_bounds__(256) void gemm_kernel(
    const unsigned short* __restrict__ A, const unsigned short* __restrict__ B,
    const float* __restrict__ bias, float* __restrict__ C) {
  __shared__ unsigned short sA[128 * 32];
  __shared__ unsigned short sB[128 * 32];

  int bid = blockIdx.x;
  const int cpx = gridDim.x >> 3;
  bid = (bid & 7) * cpx + (bid >> 3);
  const int tileM = (bid >> 3) * 128;
  const int tileN = (bid & 7) * 128;

  const int t = threadIdx.x;
  const int lane = t & 63;
  const int wid = t >> 6;
  const int wm = wid >> 1, wn = wid & 1;
  const int lrow = lane & 15;
  const int lgrp = lane >> 4;

  f32x4 acc[4][4];
#pragma unroll
  for (int a = 0; a < 4; ++a)
#pragma unroll
    for (int b = 0; b < 4; ++b) acc[a][b] = (f32x4){0.f, 0.f, 0.f, 0.f};

  const int row0 = t >> 2;
  const int kk = (t & 3) * 8;
  const size_t abase = ((size_t)(tileM + row0)) * 1024 + kk;
  const size_t bbase = ((size_t)(tileN + row0)) * 1024 + kk;

  for (int k0 = 0; k0 < 1024; k0 += 32) {
#pragma unroll
    for (int c = 0; c < 2; ++c) {
      GLD16(A + abase + (size_t)c * 64 * 1024 + k0,
            (char*)sA + c * 4096 + t * 16);
      GLD16(B + bbase + (size_t)c * 64 * 1024 + k0,
            (char*)sB + c * 4096 + t * 16);
    }
    __syncthreads();

    bf16x8 af[4], bfr[4];
#pragma unroll
    for (int mi = 0; mi < 4; ++mi)
      af[mi] = *(const bf16x8*)&sA[(wm * 64 + mi * 16 + lrow) * 32 + lgrp * 8];
#pragma unroll
    for (int ni = 0; ni < 4; ++ni)
      bfr[ni] = *(const bf16x8*)&sB[(wn * 64 + ni * 16 + lrow) * 32 + lgrp * 8];
#pragma unroll
    for (int mi = 0; mi < 4; ++mi)
#pragma unroll
      for (int ni = 0; ni < 4; ++ni)
        acc[mi][ni] = __builtin_amdgcn_mfma_f32_16x16x32_bf16(
            af[mi], bfr[ni], acc[mi][ni], 0, 0, 0);
    __syncthreads();
  }

#pragma unroll
  for (int ni = 0; ni < 4; ++ni) {
    const int colc = tileN + wn * 64 + ni * 16 + lrow;
    const float bv = bias[colc];
#pragma unroll
    for (int mi = 0; mi < 4; ++mi) {
      const int row = tileM + wm * 64 + mi * 16 + lgrp * 4;
#pragma unroll
      for (int r = 0; r < 4; ++r)
        C[(size_t)(row + r) * 1024 + colc] = acc[mi][ni][r] + bv;
    }
  }
}

// ---------------------------------------------------------------------------
extern "C" void kernel_launch(void* const* d_in, const int* in_sizes, int n_in,
                              void* d_out, int out_size, void* d_ws,
                              size_t ws_size, hipStream_t stream) {
  const float* Q = (const float*)d_in[0];
  const float* K = (const float*)d_in[1];
  const float* V = (const float*)d_in[2];
  const int* mask = (const int*)d_in[3];
  const float* W = (const float*)d_in[4];
  const float* bias = (const float*)d_in[5];
  float* out = (float*)d_out;

  __bf16* X = (__bf16*)d_ws;  // 16384x1024 bf16 = 32 MB
  unsigned short* Wb =
      (unsigned short*)((char*)d_ws + (size_t)32 * 1024 * 1024);  // 2 MB

  hipLaunchKernelGGL(attn_kernel, dim3(8 * S_LEN / 4), dim3(256), 0, stream,
                     Q, K, V, mask, X);
  hipLaunchKernelGGL(wconv_kernel, dim3(1024), dim3(256), 0, stream, W, Wb);
  hipLaunchKernelGGL(gemm_kernel, dim3(1024), dim3(256), 0, stream,
                     (const unsigned short*)X, Wb, bias, out);
}

// Round 9
// 97.610 us; speedup vs baseline: 1.0255x; 1.0255x over previous
//
#include <hip/hip_runtime.h>
#include <stdint.h>

#define S_LEN 2048
#define EMB 1024

typedef __bf16 bf16x8 __attribute__((ext_vector_type(8)));
typedef __bf16 bf16x4 __attribute__((ext_vector_type(4)));
typedef float f32x4 __attribute__((ext_vector_type(4)));

__device__ __forceinline__ unsigned short f2bf(float f) {
  unsigned int b = __float_as_uint(f);
  b += 0x7FFFu + ((b >> 16) & 1u);
  return (unsigned short)(b >> 16);
}

__device__ __forceinline__ bf16x4 c4(float4 a) {
  bf16x4 r;
  r[0] = (__bf16)a.x; r[1] = (__bf16)a.y; r[2] = (__bf16)a.z; r[3] = (__bf16)a.w;
  return r;
}

#define GLD16(gp, lp)                                                          \
  __builtin_amdgcn_global_load_lds(                                            \
      (const __attribute__((address_space(1))) void*)(gp),                     \
      (__attribute__((address_space(3))) void*)(lp), 16, 0, 0)

// ---------------------------------------------------------------------------
// Kernel 1: per-(n,s) 16x16 head-Gram attention, GEMM-style staged block.
// Block = 256 thr owns 8 consecutive positions (same s>>4). Phase 1: bulk
// coalesced staging of Q/K/V (4KB-contiguous per instr) -> bf16 LDS (Q/K
// XOR-swizzled for conflict-free b128 fragment reads). Phase 2: all-LDS
// compute (R5-verified mechanics). Phase 3: cooperative X store, 1KB
// contiguous per instruction (was 16x32B scattered segments).
// ---------------------------------------------------------------------------
__global__ __launch_bounds__(256) void attn_kernel(
    const float* __restrict__ Q, const float* __restrict__ K,
    const float* __restrict__ V, const int* __restrict__ mask,
    __bf16* __restrict__ X) {
  __shared__ __bf16 Qb[8][1024];   // XOR-swizzled rows
  __shared__ __bf16 Kb[8][1024];   // XOR-swizzled rows
  __shared__ __bf16 Vb[8][1024];   // linear
  __shared__ __bf16 As[8][16][16];
  __shared__ __bf16 Ob[8 * 1160];  // pl stride 1160 elems, i stride 72

  const int t = threadIdx.x;
  const int lane = t & 63;
  const int wv = t >> 6;
  const int pos0 = blockIdx.x * 8;
  const int n = pos0 >> 11;        // uniform in block
  const int s0 = pos0 & 2047;      // all 8 positions share s>>4
  const int col = lane & 15;
  const int grp = lane >> 4;
  const int gc = grp & 1;

  const int4 mrow = *(const int4*)(mask + col * 16 + grp * 4);

  // ---- Phase 1: cooperative staging (fp32 -> bf16) ----
  {
    const float* qsrc = Q + (size_t)pos0 * EMB;
    const float* ksrc = K + (size_t)pos0 * EMB;
    const float* vsrc = V + (size_t)pos0 * EMB;
    // within-row swizzled byte offset for Qb/Kb (G4: b ^= ((b>>7&7)<<4))
    const int bsw = (t * 8) ^ (((t >> 4) & 7) << 4);
#pragma unroll
    for (int i = 0; i < 8; ++i) {
      const float4 qv = *(const float4*)(qsrc + i * 1024 + t * 4);
      const float4 kv = *(const float4*)(ksrc + i * 1024 + t * 4);
      const float4 vv = *(const float4*)(vsrc + i * 1024 + t * 4);
      *(bf16x4*)((char*)&Qb[i][0] + bsw) = c4(qv);
      *(bf16x4*)((char*)&Kb[i][0] + bsw) = c4(kv);
      *(bf16x4*)&Vb[i][t * 4] = c4(vv);
    }
  }
  __syncthreads();

  // ---- Phase 2: all-LDS compute; wave wv owns positions 2wv, 2wv+1 ----
  // fragment byte offsets in swizzled Q/K rows: elems col*64+grp*8 (+32)
  const int fb0 = (col * 128 + grp * 16) ^ ((col & 7) << 4);
  const int fb1 = (col * 128 + grp * 16 + 64) ^ ((col & 7) << 4);
  f32x4 en[2];
#pragma unroll
  for (int q = 0; q < 2; ++q) {
    const int pl = wv * 2 + q;
    const bf16x8 qa0 = *(const bf16x8*)((const char*)&Qb[pl][0] + fb0);
    const bf16x8 qa1 = *(const bf16x8*)((const char*)&Qb[pl][0] + fb1);
    const bf16x8 kb0 = *(const bf16x8*)((const char*)&Kb[pl][0] + fb0);
    const bf16x8 kb1 = *(const bf16x8*)((const char*)&Kb[pl][0] + fb1);
    f32x4 e = {0.f, 0.f, 0.f, 0.f};
    e = __builtin_amdgcn_mfma_f32_16x16x32_bf16(kb0, qa0, e, 0, 0, 0);
    e = __builtin_amdgcn_mfma_f32_16x16x32_bf16(kb1, qa1, e, 0, 0, 0);
    en[q] = e;  // lane holds E[j=grp*4+r][i=col]
  }

#pragma unroll
  for (int q = 0; q < 2; ++q) {
    const int pl = wv * 2 + q;
    float p[4];
    p[0] = (mrow.x == 0) ? -1e30f : en[q][0] * 0.125f;
    p[1] = (mrow.y == 0) ? -1e30f : en[q][1] * 0.125f;
    p[2] = (mrow.z == 0) ? -1e30f : en[q][2] * 0.125f;
    p[3] = (mrow.w == 0) ? -1e30f : en[q][3] * 0.125f;
    float mx = fmaxf(fmaxf(p[0], p[1]), fmaxf(p[2], p[3]));
    mx = fmaxf(mx, __shfl_xor(mx, 16));
    mx = fmaxf(mx, __shfl_xor(mx, 32));
    float ex[4], sm = 0.f;
#pragma unroll
    for (int r = 0; r < 4; ++r) {
      ex[r] = __expf(p[r] - mx);
      sm += ex[r];
    }
    sm += __shfl_xor(sm, 16);
    sm += __shfl_xor(sm, 32);
    const float inv = __builtin_amdgcn_rcpf(sm);
    bf16x4 aw;
#pragma unroll
    for (int r = 0; r < 4; ++r) aw[r] = (__bf16)(ex[r] * inv);
    *(bf16x4*)&As[pl][col][grp * 4] = aw;  // A[col][grp*4+r]

    // lane needs pa[e] = A[col][grp*8+e] for grp<2; zero-pad k>=16
    const bf16x8 pt = *(const bf16x8*)&As[pl][col][gc * 8];
    bf16x8 pa;
#pragma unroll
    for (int e = 0; e < 8; ++e) pa[e] = (grp < 2) ? pt[e] : (__bf16)0.f;

    // PV: Amat[row=col][k=grp*8+e] = V[gc*8+e][d=c*16+col]
    __bf16* ob = &Ob[pl * 1160];
#pragma unroll
    for (int c = 0; c < 4; ++c) {
      bf16x8 vf;
#pragma unroll
      for (int e = 0; e < 8; ++e)
        vf[e] = Vb[pl][(gc * 8 + e) * 64 + c * 16 + col];
      f32x4 o = {0.f, 0.f, 0.f, 0.f};
      o = __builtin_amdgcn_mfma_f32_16x16x32_bf16(vf, pa, o, 0, 0, 0);
      // lane holds O[i=col][d = c*16 + grp*4 + r]
      bf16x4 w;
#pragma unroll
      for (int r = 0; r < 4; ++r) w[r] = (__bf16)o[r];
      *(bf16x4*)(ob + col * 72 + c * 16 + grp * 4) = w;
    }
  }
  __syncthreads();

  // ---- Phase 3: cooperative coalesced X store (1 KB contiguous / instr) ----
  // X row for head i: n*2048 + i*128 + (s0>>4); cols (s0&15)*64 + off
#pragma unroll
  for (int it = 0; it < 4; ++it) {
    const int chunk = it * 256 + t;     // 0..1023
    const int i = chunk >> 6;           // head row, const per wave-instr
    const int off = (chunk & 63) * 8;   // 0..504
    const int pl = off >> 6;
    const int d0 = off & 63;
    const bf16x8 v = *(const bf16x8*)&Ob[pl * 1160 + i * 72 + d0];
    const size_t row = (size_t)n * S_LEN + (size_t)i * 128 + (s0 >> 4);
    *(bf16x8*)&X[row * EMB + (size_t)((s0 & 15) * 64 + off)] = v;
  }
}

// ---------------------------------------------------------------------------
// Kernel 2: W_out fp32 -> bf16 bits
// ---------------------------------------------------------------------------
__global__ __launch_bounds__(256) void wconv_kernel(
    const float* __restrict__ W, unsigned short* __restrict__ Wb) {
  const int idx = blockIdx.x * 256 + threadIdx.x;
  float4 w = *(const float4*)(W + (size_t)idx * 4);
  ushort4 o;
  o.x = f2bf(w.x);
  o.y = f2bf(w.y);
  o.z = f2bf(w.z);
  o.w = f2bf(w.w);
  *(ushort4*)(Wb + (size_t)idx * 4) = o;
}

// ---------------------------------------------------------------------------
// Kernel 3: C[16384][1024] = X[16384][1024] * W[1024][1024]^T + bias
// ---------------------------------------------------------------------------
__global__ __launch_bounds__(256) void gemm_kernel(
    const unsigned short* __restrict__ A, const unsigned short* __restrict__ B,
    const float* __restrict__ bias, float* __restrict__ C) {
  __shared__ unsigned short sA[128 * 32];
  __shared__ unsigned short sB[128 * 32];

  int bid = blockIdx.x;
  const int cpx = gridDim.x >> 3;
  bid = (bid & 7) * cpx + (bid >> 3);
  const int tileM = (bid >> 3) * 128;
  const int tileN = (bid & 7) * 128;

  const int t = threadIdx.x;
  const int lane = t & 63;
  const int wid = t >> 6;
  const int wm = wid >> 1, wn = wid & 1;
  const int lrow = lane & 15;
  const int lgrp = lane >> 4;

  f32x4 acc[4][4];
#pragma unroll
  for (int a = 0; a < 4; ++a)
#pragma unroll
    for (int b = 0; b < 4; ++b) acc[a][b] = (f32x4){0.f, 0.f, 0.f, 0.f};

  const int row0 = t >> 2;
  const int kk = (t & 3) * 8;
  const size_t abase = ((size_t)(tileM + row0)) * 1024 + kk;
  const size_t bbase = ((size_t)(tileN + row0)) * 1024 + kk;

  for (int k0 = 0; k0 < 1024; k0 += 32) {
#pragma unroll
    for (int c = 0; c < 2; ++c) {
      GLD16(A + abase + (size_t)c * 64 * 1024 + k0,
            (char*)sA + c * 4096 + t * 16);
      GLD16(B + bbase + (size_t)c * 64 * 1024 + k0,
            (char*)sB + c * 4096 + t * 16);
    }
    __syncthreads();

    bf16x8 af[4], bfr[4];
#pragma unroll
    for (int mi = 0; mi < 4; ++mi)
      af[mi] = *(const bf16x8*)&sA[(wm * 64 + mi * 16 + lrow) * 32 + lgrp * 8];
#pragma unroll
    for (int ni = 0; ni < 4; ++ni)
      bfr[ni] = *(const bf16x8*)&sB[(wn * 64 + ni * 16 + lrow) * 32 + lgrp * 8];
#pragma unroll
    for (int mi = 0; mi < 4; ++mi)
#pragma unroll
      for (int ni = 0; ni < 4; ++ni)
        acc[mi][ni] = __builtin_amdgcn_mfma_f32_16x16x32_bf16(
            af[mi], bfr[ni], acc[mi][ni], 0, 0, 0);
    __syncthreads();
  }

#pragma unroll
  for (int ni = 0; ni < 4; ++ni) {
    const int colc = tileN + wn * 64 + ni * 16 + lrow;
    const float bv = bias[colc];
#pragma unroll
    for (int mi = 0; mi < 4; ++mi) {
      const int row = tileM + wm * 64 + mi * 16 + lgrp * 4;
#pragma unroll
      for (int r = 0; r < 4; ++r)
        C[(size_t)(row + r) * 1024 + colc] = acc[mi][ni][r] + bv;
    }
  }
}

// ---------------------------------------------------------------------------
extern "C" void kernel_launch(void* const* d_in, const int* in_sizes, int n_in,
                              void* d_out, int out_size, void* d_ws,
                              size_t ws_size, hipStream_t stream) {
  const float* Q = (const float*)d_in[0];
  const float* K = (const float*)d_in[1];
  const float* V = (const float*)d_in[2];
  const int* mask = (const int*)d_in[3];
  const float* W = (const float*)d_in[4];
  const float* bias = (const float*)d_in[5];
  float* out = (float*)d_out;

  __bf16* X = (__bf16*)d_ws;  // 16384x1024 bf16 = 32 MB
  unsigned short* Wb =
      (unsigned short*)((char*)d_ws + (size_t)32 * 1024 * 1024);  // 2 MB

  hipLaunchKernelGGL(attn_kernel, dim3(8 * S_LEN / 8), dim3(256), 0, stream,
                     Q, K, V, mask, X);
  hipLaunchKernelGGL(wconv_kernel, dim3(1024), dim3(256), 0, stream, W, Wb);
  hipLaunchKernelGGL(gemm_kernel, dim3(1024), dim3(256), 0, stream,
                     (const unsigned short*)X, Wb, bias, out);
}